// Round 3
// baseline (902.222 us; speedup 1.0000x reference)
//
#include <hip/hip_runtime.h>
#include <hip/hip_bf16.h>
#include <stdint.h>

typedef unsigned short u16;
typedef __bf16 bf16x8 __attribute__((ext_vector_type(8)));
typedef float f32x4 __attribute__((ext_vector_type(4)));
typedef u16 u16x8 __attribute__((ext_vector_type(8)));

__device__ __forceinline__ float b2f(u16 v) {
    union { float f; unsigned int u; } x; x.u = ((unsigned int)v) << 16; return x.f;
}
__device__ __forceinline__ u16 f2b(float f) {
    union { float f; unsigned int u; } x; x.f = f;
    unsigned int r = x.u + 0x7fff + ((x.u >> 16) & 1);
    return (u16)(r >> 16);
}

// Load 8 source elements as 8 packed bf16 (one 16B value for ds_write_b128).
__device__ __forceinline__ uint4 load8_as_bf16(const float* p) {
    float4 f0 = *(const float4*)p;
    float4 f1 = *(const float4*)(p + 4);
    union { u16 h[8]; uint4 v; } r;
    r.h[0] = f2b(f0.x); r.h[1] = f2b(f0.y); r.h[2] = f2b(f0.z); r.h[3] = f2b(f0.w);
    r.h[4] = f2b(f1.x); r.h[5] = f2b(f1.y); r.h[6] = f2b(f1.z); r.h[7] = f2b(f1.w);
    return r.v;
}
__device__ __forceinline__ uint4 load8_as_bf16(const u16* p) {
    return *(const uint4*)p;
}

// NT GEMM: C[M,N] = act(A[M,K] * B[N,K]^T + bias[N]); A is fp32 or bf16(u16),
// B/bias fp32, C bf16. fp32 accum via MFMA. M,N mult of 128; K mult of 32.
// 256 threads, 4 waves in 2x2, each wave 64x64 via 4x4 of 16x16x32 MFMAs.
// LDS sA/sB row-major [128][32] bf16.
template <typename TA, bool RELU>
__global__ __launch_bounds__(256, 2) void gemm_bias_nt(
    const TA* __restrict__ A, const float* __restrict__ Bw,
    const float* __restrict__ bias, u16* __restrict__ C,
    int M, int N, int K)
{
    __shared__ alignas(16) u16 sA[128 * 32];
    __shared__ alignas(16) u16 sB[128 * 32];

    const int t  = threadIdx.x;
    const int l  = t & 63;
    const int w  = t >> 6;
    const int mBase = blockIdx.y * 128;
    const int nBase = blockIdx.x * 128;
    const int wr = w >> 1, wc = w & 1;

    f32x4 acc[4][4] = {};

    // staging: thread t handles chunk t (rows 0..63) and t+256 (rows 64..127);
    // chunk c -> row c>>2, K-part (c&3)*8 elems (8 elems = 16B bf16 in LDS)
    const int srow = t >> 2;          // 0..63
    const int kpart = (t & 3) * 8;
    const TA* aBase = A + (size_t)mBase * K;
    const float* bBase = Bw + (size_t)nBase * K;

    // fragment addressing: lane holds X[frow][kgrp .. kgrp+8)
    const int frow = l & 15;
    const int kgrp = (l >> 4) * 8;

    for (int k0 = 0; k0 < K; k0 += 32) {
        uint4 a0 = load8_as_bf16(aBase + (size_t)srow * K + (k0 + kpart));
        uint4 a1 = load8_as_bf16(aBase + (size_t)(srow + 64) * K + (k0 + kpart));
        uint4 b0 = load8_as_bf16(bBase + (size_t)srow * K + (k0 + kpart));
        uint4 b1 = load8_as_bf16(bBase + (size_t)(srow + 64) * K + (k0 + kpart));

        __syncthreads();   // previous iteration's LDS reads complete

        *(uint4*)&sA[(size_t)t * 8]         = a0;
        *(uint4*)&sA[(size_t)(t + 256) * 8] = a1;
        *(uint4*)&sB[(size_t)t * 8]         = b0;
        *(uint4*)&sB[(size_t)(t + 256) * 8] = b1;

        __syncthreads();   // LDS writes visible to all waves

        bf16x8 af[4], bf[4];
#pragma unroll
        for (int r = 0; r < 4; ++r)
            af[r] = *(const bf16x8*)&sA[(wr * 64 + r * 16 + frow) * 32 + kgrp];
#pragma unroll
        for (int c = 0; c < 4; ++c)
            bf[c] = *(const bf16x8*)&sB[(wc * 64 + c * 16 + frow) * 32 + kgrp];

#pragma unroll
        for (int r = 0; r < 4; ++r)
#pragma unroll
            for (int c = 0; c < 4; ++c)
                acc[r][c] = __builtin_amdgcn_mfma_f32_16x16x32_bf16(
                    af[r], bf[c], acc[r][c], 0, 0, 0);
    }

    // epilogue: C/D layout col = l&15, row = (l>>4)*4 + reg
    const int rquad = (l >> 4) * 4;
#pragma unroll
    for (int c = 0; c < 4; ++c) {
        const int col = nBase + wc * 64 + c * 16 + (l & 15);
        const float bv = bias[col];
#pragma unroll
        for (int r = 0; r < 4; ++r) {
            const int row = mBase + wr * 64 + r * 16 + rquad;
#pragma unroll
            for (int i = 0; i < 4; ++i) {
                float v = acc[r][c][i] + bv;
                if (RELU) v = fmaxf(v, 0.0f);
                C[(size_t)(row + i) * N + col] = f2b(v);
            }
        }
    }
}

// GRU elementwise: r = sig(ir+hr); z = sig(iz+hz); n = tanh(inn + r*hn);
// h = (1-z)*n + z*h_prev. gi/gh bf16, hprev fp32; writes h fp32 (output) and
// bf16 copy (for the q GEMM). 8 elems/thread.
__global__ __launch_bounds__(256) void gru_kernel(
    const u16* __restrict__ gi, const u16* __restrict__ gh,
    const float* __restrict__ hprev, float* __restrict__ houtf,
    u16* __restrict__ houtb, int H)
{
    const size_t idx = ((size_t)blockIdx.x * 256 + threadIdx.x) * 8;
    const size_t b = idx / H;
    const size_t j = idx - b * H;
    const size_t g0 = b * (size_t)(3 * H) + j;

    u16x8 vir = *(const u16x8*)&gi[g0];
    u16x8 viz = *(const u16x8*)&gi[g0 + H];
    u16x8 vin = *(const u16x8*)&gi[g0 + 2 * H];
    u16x8 vhr = *(const u16x8*)&gh[g0];
    u16x8 vhz = *(const u16x8*)&gh[g0 + H];
    u16x8 vhn = *(const u16x8*)&gh[g0 + 2 * H];
    float4 hp0 = *(const float4*)&hprev[idx];
    float4 hp1 = *(const float4*)&hprev[idx + 4];
    float hp[8] = {hp0.x, hp0.y, hp0.z, hp0.w, hp1.x, hp1.y, hp1.z, hp1.w};
    float ho[8];
    u16x8 ob;
#pragma unroll
    for (int i = 0; i < 8; ++i) {
        float r = 1.f / (1.f + expf(-(b2f(vir[i]) + b2f(vhr[i]))));
        float z = 1.f / (1.f + expf(-(b2f(viz[i]) + b2f(vhz[i]))));
        float n = tanhf(b2f(vin[i]) + r * b2f(vhn[i]));
        float h = (1.f - z) * n + z * hp[i];
        ho[i] = h;
        ob[i] = f2b(h);
    }
    *(float4*)&houtf[idx]     = make_float4(ho[0], ho[1], ho[2], ho[3]);
    *(float4*)&houtf[idx + 4] = make_float4(ho[4], ho[5], ho[6], ho[7]);
    *(u16x8*)&houtb[idx] = ob;
}

// Decode: per row i of q[4096,4096] (bf16):
//   out[2i,  j] = max(q[i, j..j+63])                 (windows, j<64)
//   out[2i+1,j] = max over m with m % 64 == (j-1)%64 (strided residue class)
// out is fp32.
__global__ __launch_bounds__(256) void decode_kernel(
    const u16* __restrict__ q, float* __restrict__ out)
{
    __shared__ float s[4096];
    const int row = blockIdx.x;
    const int t = threadIdx.x;
    const size_t base = (size_t)row * 4096;
#pragma unroll
    for (int i = 0; i < 16; ++i) {
        int j = t + i * 256;
        s[j] = b2f(q[base + j]);
    }
    __syncthreads();
    if (t < 64) {
        float m = -INFINITY;
#pragma unroll 8
        for (int k = 0; k < 64; ++k) m = fmaxf(m, s[t + k]);
        out[(size_t)(2 * row) * 64 + t] = m;
    } else if (t < 128) {
        const int rr = t - 64;
        float m = -INFINITY;
#pragma unroll 8
        for (int k = 0; k < 64; ++k) m = fmaxf(m, s[rr + 64 * k]);
        const int j = (rr + 1) & 63;   // residue rr corresponds to output col j
        out[(size_t)(2 * row + 1) * 64 + j] = m;
    }
}

extern "C" void kernel_launch(void* const* d_in, const int* in_sizes, int n_in,
                              void* d_out, int out_size, void* d_ws, size_t ws_size,
                              hipStream_t stream) {
    constexpr int Bn = 4096, IN = 1024, H = 2048, A = 64, A2 = A * A;

    const float* inputs = (const float*)d_in[0];
    const float* h0     = (const float*)d_in[1];
    const float* W1     = (const float*)d_in[2];
    const float* b1     = (const float*)d_in[3];
    const float* Wih    = (const float*)d_in[4];
    const float* Whh    = (const float*)d_in[5];
    const float* bih    = (const float*)d_in[6];
    const float* bhh    = (const float*)d_in[7];
    const float* W2     = (const float*)d_in[8];
    const float* b2     = (const float*)d_in[9];

    float* out  = (float*)d_out;                 // [2B, A] fp32
    float* hout = out + (size_t)2 * Bn * A;      // [B, H] fp32 (output 1)

    u16* x   = (u16*)d_ws;                       // [B, H] bf16
    u16* gi  = x + (size_t)Bn * H;               // [B, 3H] bf16
    u16* gh  = gi + (size_t)Bn * 3 * H;          // [B, 3H] bf16
    u16* hbf = gh + (size_t)Bn * 3 * H;          // [B, H] bf16 copy of h
    u16* q   = gi;                               // [B, A2] bf16, reuses gi

    dim3 blk(256);
    // 1) x = relu(inputs @ W1^T + b1)   M=4096 N=2048 K=1024  (A fp32)
    gemm_bias_nt<float, true><<<dim3(H / 128, Bn / 128), blk, 0, stream>>>(
        inputs, W1, b1, x, Bn, H, IN);
    // 2) gi = x @ Wih^T + bih           M=4096 N=6144 K=2048  (A bf16)
    gemm_bias_nt<u16, false><<<dim3(3 * H / 128, Bn / 128), blk, 0, stream>>>(
        x, Wih, bih, gi, Bn, 3 * H, H);
    // 3) gh = h0 @ Whh^T + bhh          M=4096 N=6144 K=2048  (A fp32)
    gemm_bias_nt<float, false><<<dim3(3 * H / 128, Bn / 128), blk, 0, stream>>>(
        h0, Whh, bhh, gh, Bn, 3 * H, H);
    // 4) GRU elementwise -> h (fp32 into d_out, bf16 copy into ws)
    gru_kernel<<<dim3((Bn * H / 8) / 256), blk, 0, stream>>>(
        gi, gh, h0, hout, hbf, H);
    // 5) q = h @ W2^T + b2              M=4096 N=4096 K=2048  (A bf16)
    gemm_bias_nt<u16, false><<<dim3(A2 / 128, Bn / 128), blk, 0, stream>>>(
        hbf, W2, b2, q, Bn, A2, H);
    // 6) decode maxes -> out (fp32)
    decode_kernel<<<dim3(Bn), blk, 0, stream>>>(q, out);
}

// Round 4
// 783.309 us; speedup vs baseline: 1.1518x; 1.1518x over previous
//
#include <hip/hip_runtime.h>
#include <stdint.h>

typedef unsigned short u16;
typedef __bf16 bf16x8 __attribute__((ext_vector_type(8)));
typedef float f32x4 __attribute__((ext_vector_type(4)));
typedef u16 u16x8 __attribute__((ext_vector_type(8)));

__device__ __forceinline__ float b2f(u16 v) {
    union { float f; unsigned int u; } x; x.u = ((unsigned int)v) << 16; return x.f;
}
__device__ __forceinline__ u16 f2b(float f) {
    union { float f; unsigned int u; } x; x.f = f;
    unsigned int r = x.u + 0x7fff + ((x.u >> 16) & 1);
    return (u16)(r >> 16);
}

__device__ __forceinline__ void gll16(const void* g, void* l) {
    __builtin_amdgcn_global_load_lds(
        (const __attribute__((address_space(1))) void*)g,
        (__attribute__((address_space(3))) void*)l,
        16, 0, 0);
}

__device__ __forceinline__ bf16x8 pack8(float4 f0, float4 f1) {
    union { u16 h[8]; bf16x8 v; } u;
    u.h[0] = f2b(f0.x); u.h[1] = f2b(f0.y); u.h[2] = f2b(f0.z); u.h[3] = f2b(f0.w);
    u.h[4] = f2b(f1.x); u.h[5] = f2b(f1.y); u.h[6] = f2b(f1.z); u.h[7] = f2b(f1.w);
    return u.v;
}

// NT GEMM: C[M,N] = act(A[M,K] * B[N,K]^T + bias[N]).
// A: fp32 or bf16(u16); B,bias: fp32; C: bf16. fp32 MFMA accum.
// M,N mult of 128; K mult of 32. 256 thr, 4 waves 2x2, wave=64x64 (4x4 MFMA).
// Staging: global_load_lds DMA, 16B chunks, XOR-swizzled LDS:
//   fp32 tile [128][32]: phys_chunk = r*8 + (c ^ (r&7))       (chunk = 4 f32)
//   bf16 tile [128][32]: phys_chunk = r*4 + (c ^ ((r>>1)&3))  (chunk = 8 bf16)
// fp32 operands converted to bf16 at fragment-read (cvt co-issues with MFMA).
template <typename TA, bool RELU>
__global__ __launch_bounds__(256, 3) void gemm_bias_nt(
    const TA* __restrict__ A, const float* __restrict__ Bw,
    const float* __restrict__ bias, u16* __restrict__ C,
    int M, int N, int K)
{
    constexpr bool AF = (sizeof(TA) == 4);
    constexpr int SA_BYTES = AF ? 16384 : 8192;
    __shared__ alignas(16) char smem[SA_BYTES + 16384];
    char* const sA = smem;
    char* const sB = smem + SA_BYTES;

    const int t = threadIdx.x;
    const int l = t & 63;
    const int w = t >> 6;
    const int mBase = blockIdx.y * 128;
    const int nBase = blockIdx.x * 128;
    const int wr = w >> 1, wc = w & 1;

    f32x4 acc[4][4] = {};

    const int frow = l & 15;
    const int cIdx = l >> 4;          // which 8-elem K-group this lane holds

    for (int k0 = 0; k0 < K; k0 += 32) {
        // ---- A staging (DMA) ----
        if (AF) {
#pragma unroll
            for (int i = 0; i < 4; ++i) {
                const int phys = i * 256 + t;
                const int r = phys >> 3;
                const int c = (phys & 7) ^ (r & 7);
                gll16((const float*)A + (size_t)(mBase + r) * K + (k0 + c * 4),
                      sA + (i * 256 + w * 64) * 16);
            }
        } else {
#pragma unroll
            for (int i = 0; i < 2; ++i) {
                const int phys = i * 256 + t;
                const int r = phys >> 2;
                const int c = (phys & 3) ^ ((r >> 1) & 3);
                gll16((const u16*)A + (size_t)(mBase + r) * K + (k0 + c * 8),
                      sA + (i * 256 + w * 64) * 16);
            }
        }
        // ---- B staging (fp32, DMA) ----
#pragma unroll
        for (int i = 0; i < 4; ++i) {
            const int phys = i * 256 + t;
            const int r = phys >> 3;
            const int c = (phys & 7) ^ (r & 7);
            gll16(Bw + (size_t)(nBase + r) * K + (k0 + c * 4),
                  sB + (i * 256 + w * 64) * 16);
        }

        __syncthreads();   // drains vmcnt -> DMA landed; LDS consistent

        bf16x8 af[4], bf[4];
        if (AF) {
            const int c0 = cIdx * 2;
#pragma unroll
            for (int rr = 0; rr < 4; ++rr) {
                const int fr = wr * 64 + rr * 16 + frow;
                const float4 f0 = *(const float4*)(sA + (fr * 8 + (c0 ^ (fr & 7))) * 16);
                const float4 f1 = *(const float4*)(sA + (fr * 8 + ((c0 + 1) ^ (fr & 7))) * 16);
                af[rr] = pack8(f0, f1);
            }
        } else {
#pragma unroll
            for (int rr = 0; rr < 4; ++rr) {
                const int fr = wr * 64 + rr * 16 + frow;
                af[rr] = *(const bf16x8*)(sA + (fr * 4 + (cIdx ^ ((fr >> 1) & 3))) * 16);
            }
        }
        {
            const int c0 = cIdx * 2;
#pragma unroll
            for (int cc = 0; cc < 4; ++cc) {
                const int fr = wc * 64 + cc * 16 + frow;
                const float4 f0 = *(const float4*)(sB + (fr * 8 + (c0 ^ (fr & 7))) * 16);
                const float4 f1 = *(const float4*)(sB + (fr * 8 + ((c0 + 1) ^ (fr & 7))) * 16);
                bf[cc] = pack8(f0, f1);
            }
        }

#pragma unroll
        for (int r = 0; r < 4; ++r)
#pragma unroll
            for (int c = 0; c < 4; ++c)
                acc[r][c] = __builtin_amdgcn_mfma_f32_16x16x32_bf16(
                    af[r], bf[c], acc[r][c], 0, 0, 0);

        __syncthreads();   // reads done before next iter's DMA overwrites LDS
    }

    // epilogue: C/D layout col = l&15, row = (l>>4)*4 + reg
    const int rquad = (l >> 4) * 4;
#pragma unroll
    for (int c = 0; c < 4; ++c) {
        const int col = nBase + wc * 64 + c * 16 + (l & 15);
        const float bv = bias[col];
#pragma unroll
        for (int r = 0; r < 4; ++r) {
            const int row = mBase + wr * 64 + r * 16 + rquad;
#pragma unroll
            for (int i = 0; i < 4; ++i) {
                float v = acc[r][c][i] + bv;
                if (RELU) v = fmaxf(v, 0.0f);
                C[(size_t)(row + i) * N + col] = f2b(v);
            }
        }
    }
}

// GRU elementwise: r = sig(ir+hr); z = sig(iz+hz); n = tanh(inn + r*hn);
// h = (1-z)*n + z*h_prev. gi/gh bf16, hprev fp32; writes h fp32 (output) and
// bf16 copy (for the q GEMM). 8 elems/thread.
__global__ __launch_bounds__(256) void gru_kernel(
    const u16* __restrict__ gi, const u16* __restrict__ gh,
    const float* __restrict__ hprev, float* __restrict__ houtf,
    u16* __restrict__ houtb, int H)
{
    const size_t idx = ((size_t)blockIdx.x * 256 + threadIdx.x) * 8;
    const size_t b = idx / H;
    const size_t j = idx - b * H;
    const size_t g0 = b * (size_t)(3 * H) + j;

    u16x8 vir = *(const u16x8*)&gi[g0];
    u16x8 viz = *(const u16x8*)&gi[g0 + H];
    u16x8 vin = *(const u16x8*)&gi[g0 + 2 * H];
    u16x8 vhr = *(const u16x8*)&gh[g0];
    u16x8 vhz = *(const u16x8*)&gh[g0 + H];
    u16x8 vhn = *(const u16x8*)&gh[g0 + 2 * H];
    float4 hp0 = *(const float4*)&hprev[idx];
    float4 hp1 = *(const float4*)&hprev[idx + 4];
    float hp[8] = {hp0.x, hp0.y, hp0.z, hp0.w, hp1.x, hp1.y, hp1.z, hp1.w};
    float ho[8];
    u16x8 ob;
#pragma unroll
    for (int i = 0; i < 8; ++i) {
        float r = 1.f / (1.f + expf(-(b2f(vir[i]) + b2f(vhr[i]))));
        float z = 1.f / (1.f + expf(-(b2f(viz[i]) + b2f(vhz[i]))));
        float n = tanhf(b2f(vin[i]) + r * b2f(vhn[i]));
        float h = (1.f - z) * n + z * hp[i];
        ho[i] = h;
        ob[i] = f2b(h);
    }
    *(float4*)&houtf[idx]     = make_float4(ho[0], ho[1], ho[2], ho[3]);
    *(float4*)&houtf[idx + 4] = make_float4(ho[4], ho[5], ho[6], ho[7]);
    *(u16x8*)&houtb[idx] = ob;
}

// Decode: per row i of q[4096,4096] (bf16):
//   out[2i,  j] = max(q[i, j..j+63])                 (windows, j<64)
//   out[2i+1,j] = max over m with m % 64 == (j-1)%64 (strided residue class)
__global__ __launch_bounds__(256) void decode_kernel(
    const u16* __restrict__ q, float* __restrict__ out)
{
    __shared__ float s[4096];
    const int row = blockIdx.x;
    const int t = threadIdx.x;
    const size_t base = (size_t)row * 4096;
#pragma unroll
    for (int i = 0; i < 16; ++i) {
        int j = t + i * 256;
        s[j] = b2f(q[base + j]);
    }
    __syncthreads();
    if (t < 64) {
        float m = -INFINITY;
#pragma unroll 8
        for (int k = 0; k < 64; ++k) m = fmaxf(m, s[t + k]);
        out[(size_t)(2 * row) * 64 + t] = m;
    } else if (t < 128) {
        const int rr = t - 64;
        float m = -INFINITY;
#pragma unroll 8
        for (int k = 0; k < 64; ++k) m = fmaxf(m, s[rr + 64 * k]);
        const int j = (rr + 1) & 63;   // residue rr corresponds to output col j
        out[(size_t)(2 * row + 1) * 64 + j] = m;
    }
}

extern "C" void kernel_launch(void* const* d_in, const int* in_sizes, int n_in,
                              void* d_out, int out_size, void* d_ws, size_t ws_size,
                              hipStream_t stream) {
    constexpr int Bn = 4096, IN = 1024, H = 2048, A = 64, A2 = A * A;

    const float* inputs = (const float*)d_in[0];
    const float* h0     = (const float*)d_in[1];
    const float* W1     = (const float*)d_in[2];
    const float* b1     = (const float*)d_in[3];
    const float* Wih    = (const float*)d_in[4];
    const float* Whh    = (const float*)d_in[5];
    const float* bih    = (const float*)d_in[6];
    const float* bhh    = (const float*)d_in[7];
    const float* W2     = (const float*)d_in[8];
    const float* b2     = (const float*)d_in[9];

    float* out  = (float*)d_out;                 // [2B, A] fp32
    float* hout = out + (size_t)2 * Bn * A;      // [B, H] fp32 (output 1)

    u16* x   = (u16*)d_ws;                       // [B, H] bf16
    u16* gi  = x + (size_t)Bn * H;               // [B, 3H] bf16
    u16* gh  = gi + (size_t)Bn * 3 * H;          // [B, 3H] bf16
    u16* hbf = gh + (size_t)Bn * 3 * H;          // [B, H] bf16 copy of h
    u16* q   = gi;                               // [B, A2] bf16, reuses gi

    dim3 blk(256);
    // 1) x = relu(inputs @ W1^T + b1)   M=4096 N=2048 K=1024  (A fp32)
    gemm_bias_nt<float, true><<<dim3(H / 128, Bn / 128), blk, 0, stream>>>(
        inputs, W1, b1, x, Bn, H, IN);
    // 2) gi = x @ Wih^T + bih           M=4096 N=6144 K=2048  (A bf16)
    gemm_bias_nt<u16, false><<<dim3(3 * H / 128, Bn / 128), blk, 0, stream>>>(
        x, Wih, bih, gi, Bn, 3 * H, H);
    // 3) gh = h0 @ Whh^T + bhh          M=4096 N=6144 K=2048  (A fp32)
    gemm_bias_nt<float, false><<<dim3(3 * H / 128, Bn / 128), blk, 0, stream>>>(
        h0, Whh, bhh, gh, Bn, 3 * H, H);
    // 4) GRU elementwise -> h (fp32 into d_out, bf16 copy into ws)
    gru_kernel<<<dim3((Bn * H / 8) / 256), blk, 0, stream>>>(
        gi, gh, h0, hout, hbf, H);
    // 5) q = h @ W2^T + b2              M=4096 N=4096 K=2048  (A bf16)
    gemm_bias_nt<u16, false><<<dim3(A2 / 128, Bn / 128), blk, 0, stream>>>(
        hbf, W2, b2, q, Bn, A2, H);
    // 6) decode maxes -> out (fp32)
    decode_kernel<<<dim3(Bn), blk, 0, stream>>>(q, out);
}

// Round 5
// 754.157 us; speedup vs baseline: 1.1963x; 1.0387x over previous
//
#include <hip/hip_runtime.h>
#include <stdint.h>

typedef unsigned short u16;
typedef __bf16 bf16x8 __attribute__((ext_vector_type(8)));
typedef float f32x4 __attribute__((ext_vector_type(4)));
typedef u16 u16x8 __attribute__((ext_vector_type(8)));

__device__ __forceinline__ float b2f(u16 v) {
    union { float f; unsigned int u; } x; x.u = ((unsigned int)v) << 16; return x.f;
}
__device__ __forceinline__ u16 f2b(float f) {
    union { float f; unsigned int u; } x; x.f = f;
    unsigned int r = x.u + 0x7fff + ((x.u >> 16) & 1);
    return (u16)(r >> 16);
}

__device__ __forceinline__ void gll16(const void* g, void* l) {
    __builtin_amdgcn_global_load_lds(
        (const __attribute__((address_space(1))) void*)g,
        (__attribute__((address_space(3))) void*)l,
        16, 0, 0);
}

// fp32x8 -> bf16x8, round-half-up (hi16(bits+0x8000)), packed via v_perm_b32:
// 12 VALU ops per 8 elements (vs ~32 for full RNE).
__device__ __forceinline__ bf16x8 pack8(float4 f0, float4 f1) {
    union { float4 f; uint4 u; } a, b;
    a.f = f0; b.f = f1;
    const unsigned sel = 0x07060302u;   // D = {s0.hi16, s1.hi16}
    union { unsigned u[4]; bf16x8 v; } r;
    r.u[0] = __builtin_amdgcn_perm(a.u.y + 0x8000u, a.u.x + 0x8000u, sel);
    r.u[1] = __builtin_amdgcn_perm(a.u.w + 0x8000u, a.u.z + 0x8000u, sel);
    r.u[2] = __builtin_amdgcn_perm(b.u.y + 0x8000u, b.u.x + 0x8000u, sel);
    r.u[3] = __builtin_amdgcn_perm(b.u.w + 0x8000u, b.u.z + 0x8000u, sel);
    return r.v;
}

// NT GEMM: C[M,N] = act(A[M,K] * B[N,K]^T + bias[N]).
// A: fp32 or bf16(u16); B,bias: fp32; C: bf16. fp32 MFMA accum.
// M,N mult of 128; K mult of 32. 256 thr, 4 waves 2x2, wave=64x64 (4x4 MFMA).
// Staging: global_load_lds DMA, 16B chunks, XOR-swizzled LDS:
//   fp32 tile [128][32]: phys_chunk = r*8 + (c ^ (r&7))       (chunk = 4 f32)
//   bf16 tile [128][32]: phys_chunk = r*4 + (c ^ ((r>>1)&3))  (chunk = 8 bf16)
// fp32 operands converted to bf16 at fragment-read (perm-pack, cheap VALU).
template <typename TA, bool RELU>
__global__ __launch_bounds__(256, 3) void gemm_bias_nt(
    const TA* __restrict__ A, const float* __restrict__ Bw,
    const float* __restrict__ bias, u16* __restrict__ C,
    int M, int N, int K)
{
    constexpr bool AF = (sizeof(TA) == 4);
    constexpr int SA_BYTES = AF ? 16384 : 8192;
    __shared__ alignas(16) char smem[SA_BYTES + 16384];
    char* const sA = smem;
    char* const sB = smem + SA_BYTES;

    const int t = threadIdx.x;
    const int l = t & 63;
    const int w = t >> 6;
    const int mBase = blockIdx.y * 128;
    const int nBase = blockIdx.x * 128;
    const int wr = w >> 1, wc = w & 1;

    f32x4 acc[4][4] = {};

    const int frow = l & 15;
    const int cIdx = l >> 4;          // which 8-elem K-group this lane holds

    for (int k0 = 0; k0 < K; k0 += 32) {
        // ---- A staging (DMA) ----
        if (AF) {
#pragma unroll
            for (int i = 0; i < 4; ++i) {
                const int phys = i * 256 + t;
                const int r = phys >> 3;
                const int c = (phys & 7) ^ (r & 7);
                gll16((const float*)A + (size_t)(mBase + r) * K + (k0 + c * 4),
                      sA + (i * 256 + w * 64) * 16);
            }
        } else {
#pragma unroll
            for (int i = 0; i < 2; ++i) {
                const int phys = i * 256 + t;
                const int r = phys >> 2;
                const int c = (phys & 3) ^ ((r >> 1) & 3);
                gll16((const u16*)A + (size_t)(mBase + r) * K + (k0 + c * 8),
                      sA + (i * 256 + w * 64) * 16);
            }
        }
        // ---- B staging (fp32, DMA) ----
#pragma unroll
        for (int i = 0; i < 4; ++i) {
            const int phys = i * 256 + t;
            const int r = phys >> 3;
            const int c = (phys & 7) ^ (r & 7);
            gll16(Bw + (size_t)(nBase + r) * K + (k0 + c * 4),
                  sB + (i * 256 + w * 64) * 16);
        }

        __syncthreads();   // drains vmcnt -> DMA landed; LDS consistent

        bf16x8 af[4], bf[4];
        if (AF) {
            const int c0 = cIdx * 2;
#pragma unroll
            for (int rr = 0; rr < 4; ++rr) {
                const int fr = wr * 64 + rr * 16 + frow;
                const float4 f0 = *(const float4*)(sA + (fr * 8 + (c0 ^ (fr & 7))) * 16);
                const float4 f1 = *(const float4*)(sA + (fr * 8 + ((c0 + 1) ^ (fr & 7))) * 16);
                af[rr] = pack8(f0, f1);
            }
        } else {
#pragma unroll
            for (int rr = 0; rr < 4; ++rr) {
                const int fr = wr * 64 + rr * 16 + frow;
                af[rr] = *(const bf16x8*)(sA + (fr * 4 + (cIdx ^ ((fr >> 1) & 3))) * 16);
            }
        }
        {
            const int c0 = cIdx * 2;
#pragma unroll
            for (int cc = 0; cc < 4; ++cc) {
                const int fr = wc * 64 + cc * 16 + frow;
                const float4 f0 = *(const float4*)(sB + (fr * 8 + (c0 ^ (fr & 7))) * 16);
                const float4 f1 = *(const float4*)(sB + (fr * 8 + ((c0 + 1) ^ (fr & 7))) * 16);
                bf[cc] = pack8(f0, f1);
            }
        }

#pragma unroll
        for (int r = 0; r < 4; ++r)
#pragma unroll
            for (int c = 0; c < 4; ++c)
                acc[r][c] = __builtin_amdgcn_mfma_f32_16x16x32_bf16(
                    af[r], bf[c], acc[r][c], 0, 0, 0);

        __syncthreads();   // reads done before next iter's DMA overwrites LDS
    }

    // epilogue: C/D layout col = l&15, row = (l>>4)*4 + reg
    const int rquad = (l >> 4) * 4;
#pragma unroll
    for (int c = 0; c < 4; ++c) {
        const int col = nBase + wc * 64 + c * 16 + (l & 15);
        const float bv = bias[col];
#pragma unroll
        for (int r = 0; r < 4; ++r) {
            const int row = mBase + wr * 64 + r * 16 + rquad;
#pragma unroll
            for (int i = 0; i < 4; ++i) {
                float v = acc[r][c][i] + bv;
                if (RELU) v = fmaxf(v, 0.0f);
                C[(size_t)(row + i) * N + col] = f2b(v);
            }
        }
    }
}

// GRU elementwise: r = sig(ir+hr); z = sig(iz+hz); n = tanh(inn + r*hn);
// h = (1-z)*n + z*h_prev. gi/gh bf16, hprev fp32; writes h fp32 (output) and
// bf16 copy (for the q GEMM). 8 elems/thread.
__global__ __launch_bounds__(256) void gru_kernel(
    const u16* __restrict__ gi, const u16* __restrict__ gh,
    const float* __restrict__ hprev, float* __restrict__ houtf,
    u16* __restrict__ houtb, int H)
{
    const size_t idx = ((size_t)blockIdx.x * 256 + threadIdx.x) * 8;
    const size_t b = idx / H;
    const size_t j = idx - b * H;
    const size_t g0 = b * (size_t)(3 * H) + j;

    u16x8 vir = *(const u16x8*)&gi[g0];
    u16x8 viz = *(const u16x8*)&gi[g0 + H];
    u16x8 vin = *(const u16x8*)&gi[g0 + 2 * H];
    u16x8 vhr = *(const u16x8*)&gh[g0];
    u16x8 vhz = *(const u16x8*)&gh[g0 + H];
    u16x8 vhn = *(const u16x8*)&gh[g0 + 2 * H];
    float4 hp0 = *(const float4*)&hprev[idx];
    float4 hp1 = *(const float4*)&hprev[idx + 4];
    float hp[8] = {hp0.x, hp0.y, hp0.z, hp0.w, hp1.x, hp1.y, hp1.z, hp1.w};
    float ho[8];
    u16x8 ob;
#pragma unroll
    for (int i = 0; i < 8; ++i) {
        float r = 1.f / (1.f + expf(-(b2f(vir[i]) + b2f(vhr[i]))));
        float z = 1.f / (1.f + expf(-(b2f(viz[i]) + b2f(vhz[i]))));
        float n = tanhf(b2f(vin[i]) + r * b2f(vhn[i]));
        float h = (1.f - z) * n + z * hp[i];
        ho[i] = h;
        ob[i] = f2b(h);
    }
    *(float4*)&houtf[idx]     = make_float4(ho[0], ho[1], ho[2], ho[3]);
    *(float4*)&houtf[idx + 4] = make_float4(ho[4], ho[5], ho[6], ho[7]);
    *(u16x8*)&houtb[idx] = ob;
}

// Decode: per row i of q[4096,4096] (bf16):
//   out[2i,  j] = max(q[i, j..j+63])                 (windows, j<64)
//   out[2i+1,j] = max over m with m % 64 == (j-1)%64 (strided residue class)
__global__ __launch_bounds__(256) void decode_kernel(
    const u16* __restrict__ q, float* __restrict__ out)
{
    __shared__ float s[4096];
    const int row = blockIdx.x;
    const int t = threadIdx.x;
    const size_t base = (size_t)row * 4096;
#pragma unroll
    for (int i = 0; i < 16; ++i) {
        int j = t + i * 256;
        s[j] = b2f(q[base + j]);
    }
    __syncthreads();
    if (t < 64) {
        float m = -INFINITY;
#pragma unroll 8
        for (int k = 0; k < 64; ++k) m = fmaxf(m, s[t + k]);
        out[(size_t)(2 * row) * 64 + t] = m;
    } else if (t < 128) {
        const int rr = t - 64;
        float m = -INFINITY;
#pragma unroll 8
        for (int k = 0; k < 64; ++k) m = fmaxf(m, s[rr + 64 * k]);
        const int j = (rr + 1) & 63;   // residue rr corresponds to output col j
        out[(size_t)(2 * row + 1) * 64 + j] = m;
    }
}

extern "C" void kernel_launch(void* const* d_in, const int* in_sizes, int n_in,
                              void* d_out, int out_size, void* d_ws, size_t ws_size,
                              hipStream_t stream) {
    constexpr int Bn = 4096, IN = 1024, H = 2048, A = 64, A2 = A * A;

    const float* inputs = (const float*)d_in[0];
    const float* h0     = (const float*)d_in[1];
    const float* W1     = (const float*)d_in[2];
    const float* b1     = (const float*)d_in[3];
    const float* Wih    = (const float*)d_in[4];
    const float* Whh    = (const float*)d_in[5];
    const float* bih    = (const float*)d_in[6];
    const float* bhh    = (const float*)d_in[7];
    const float* W2     = (const float*)d_in[8];
    const float* b2     = (const float*)d_in[9];

    float* out  = (float*)d_out;                 // [2B, A] fp32
    float* hout = out + (size_t)2 * Bn * A;      // [B, H] fp32 (output 1)

    u16* x   = (u16*)d_ws;                       // [B, H] bf16
    u16* gi  = x + (size_t)Bn * H;               // [B, 3H] bf16
    u16* gh  = gi + (size_t)Bn * 3 * H;          // [B, 3H] bf16
    u16* hbf = gh + (size_t)Bn * 3 * H;          // [B, H] bf16 copy of h
    u16* q   = gi;                               // [B, A2] bf16, reuses gi

    dim3 blk(256);
    // 1) x = relu(inputs @ W1^T + b1)   M=4096 N=2048 K=1024  (A fp32)
    gemm_bias_nt<float, true><<<dim3(H / 128, Bn / 128), blk, 0, stream>>>(
        inputs, W1, b1, x, Bn, H, IN);
    // 2) gi = x @ Wih^T + bih           M=4096 N=6144 K=2048  (A bf16)
    gemm_bias_nt<u16, false><<<dim3(3 * H / 128, Bn / 128), blk, 0, stream>>>(
        x, Wih, bih, gi, Bn, 3 * H, H);
    // 3) gh = h0 @ Whh^T + bhh          M=4096 N=6144 K=2048  (A fp32)
    gemm_bias_nt<float, false><<<dim3(3 * H / 128, Bn / 128), blk, 0, stream>>>(
        h0, Whh, bhh, gh, Bn, 3 * H, H);
    // 4) GRU elementwise -> h (fp32 into d_out, bf16 copy into ws)
    gru_kernel<<<dim3((Bn * H / 8) / 256), blk, 0, stream>>>(
        gi, gh, h0, hout, hbf, H);
    // 5) q = h @ W2^T + b2              M=4096 N=4096 K=2048  (A bf16)
    gemm_bias_nt<u16, false><<<dim3(A2 / 128, Bn / 128), blk, 0, stream>>>(
        hbf, W2, b2, q, Bn, A2, H);
    // 6) decode maxes -> out (fp32)
    decode_kernel<<<dim3(Bn), blk, 0, stream>>>(q, out);
}

// Round 6
// 603.442 us; speedup vs baseline: 1.4951x; 1.2498x over previous
//
#include <hip/hip_runtime.h>
#include <stdint.h>

typedef unsigned short u16;
typedef __bf16 bf16x8 __attribute__((ext_vector_type(8)));
typedef float f32x4 __attribute__((ext_vector_type(4)));
typedef u16 u16x8 __attribute__((ext_vector_type(8)));

__device__ __forceinline__ float b2f(u16 v) {
    union { float f; unsigned int u; } x; x.u = ((unsigned int)v) << 16; return x.f;
}
__device__ __forceinline__ u16 f2b(float f) {
    union { float f; unsigned int u; } x; x.f = f;
    unsigned int r = x.u + 0x7fff + ((x.u >> 16) & 1);
    return (u16)(r >> 16);
}

__device__ __forceinline__ void gll16(const void* g, void* l) {
    __builtin_amdgcn_global_load_lds(
        (const __attribute__((address_space(1))) void*)g,
        (__attribute__((address_space(3))) void*)l,
        16, 0, 0);
}

// fp32x8 -> bf16x8, round-half-up (hi16(bits+0x8000)), packed via v_perm_b32.
__device__ __forceinline__ bf16x8 pack8(float4 f0, float4 f1) {
    union { float4 f; uint4 u; } a, b;
    a.f = f0; b.f = f1;
    const unsigned sel = 0x07060302u;   // D = {s0.hi16, s1.hi16}
    union { unsigned u[4]; bf16x8 v; } r;
    r.u[0] = __builtin_amdgcn_perm(a.u.y + 0x8000u, a.u.x + 0x8000u, sel);
    r.u[1] = __builtin_amdgcn_perm(a.u.w + 0x8000u, a.u.z + 0x8000u, sel);
    r.u[2] = __builtin_amdgcn_perm(b.u.y + 0x8000u, b.u.x + 0x8000u, sel);
    r.u[3] = __builtin_amdgcn_perm(b.u.w + 0x8000u, b.u.z + 0x8000u, sel);
    return r.v;
}

// fp32 -> bf16 bulk convert, 8 elems/thread (n must be multiple of 2048).
__global__ __launch_bounds__(256) void cvt_kernel(
    const float* __restrict__ s, u16* __restrict__ d)
{
    const size_t i = ((size_t)blockIdx.x * 256 + threadIdx.x) * 8;
    float4 f0 = *(const float4*)(s + i);
    float4 f1 = *(const float4*)(s + i + 4);
    union { bf16x8 v; u16x8 u; } r;
    r.v = pack8(f0, f1);
    *(u16x8*)(d + i) = r.u;
}

// NT GEMM, pure bf16: C[M,N] = act(A[M,K] * B[N,K]^T + bias[N]), fp32 accum.
// M,N mult of 128; K mult of 32. 256 thr, 4 waves 2x2, wave=64x64 (4x4 MFMA).
// Staging: global_load_lds DMA, 16B chunks, XOR-swizzled bf16 LDS tile
// [128][32]: phys_chunk = r*4 + (c ^ ((r>>1)&3))  (chunk = 8 bf16).
template <bool RELU>
__global__ __launch_bounds__(256, 4) void gemm_bt(
    const u16* __restrict__ A, const u16* __restrict__ Bw,
    const float* __restrict__ bias, u16* __restrict__ C,
    int M, int N, int K)
{
    __shared__ alignas(16) u16 sA[128 * 32];
    __shared__ alignas(16) u16 sB[128 * 32];

    const int t = threadIdx.x;
    const int l = t & 63;
    const int w = t >> 6;
    const int mBase = blockIdx.y * 128;
    const int nBase = blockIdx.x * 128;
    const int wr = w >> 1, wc = w & 1;

    f32x4 acc[4][4] = {};

    const int frow = l & 15;
    const int cIdx = l >> 4;          // which 8-elem K-group this lane holds

    for (int k0 = 0; k0 < K; k0 += 32) {
#pragma unroll
        for (int i = 0; i < 2; ++i) {
            const int phys = i * 256 + t;
            const int r = phys >> 2;
            const int c = (phys & 3) ^ ((r >> 1) & 3);
            gll16(A + (size_t)(mBase + r) * K + (k0 + c * 8),
                  (char*)sA + (i * 256 + w * 64) * 16);
            gll16(Bw + (size_t)(nBase + r) * K + (k0 + c * 8),
                  (char*)sB + (i * 256 + w * 64) * 16);
        }

        __syncthreads();   // drains vmcnt -> DMA landed; LDS consistent

        bf16x8 af[4], bf[4];
#pragma unroll
        for (int rr = 0; rr < 4; ++rr) {
            const int fr = wr * 64 + rr * 16 + frow;
            af[rr] = *(const bf16x8*)((char*)sA + (fr * 4 + (cIdx ^ ((fr >> 1) & 3))) * 16);
        }
#pragma unroll
        for (int cc = 0; cc < 4; ++cc) {
            const int fr = wc * 64 + cc * 16 + frow;
            bf[cc] = *(const bf16x8*)((char*)sB + (fr * 4 + (cIdx ^ ((fr >> 1) & 3))) * 16);
        }

#pragma unroll
        for (int r = 0; r < 4; ++r)
#pragma unroll
            for (int c = 0; c < 4; ++c)
                acc[r][c] = __builtin_amdgcn_mfma_f32_16x16x32_bf16(
                    af[r], bf[c], acc[r][c], 0, 0, 0);

        __syncthreads();   // reads done before next iter's DMA overwrites LDS
    }

    // epilogue: C/D layout col = l&15, row = (l>>4)*4 + reg
    const int rquad = (l >> 4) * 4;
#pragma unroll
    for (int c = 0; c < 4; ++c) {
        const int col = nBase + wc * 64 + c * 16 + (l & 15);
        const float bv = bias[col];
#pragma unroll
        for (int r = 0; r < 4; ++r) {
            const int row = mBase + wr * 64 + r * 16 + rquad;
#pragma unroll
            for (int i = 0; i < 4; ++i) {
                float v = acc[r][c][i] + bv;
                if (RELU) v = fmaxf(v, 0.0f);
                C[(size_t)(row + i) * N + col] = f2b(v);
            }
        }
    }
}

// GRU elementwise: r = sig(ir+hr); z = sig(iz+hz); n = tanh(inn + r*hn);
// h = (1-z)*n + z*h_prev. gi/gh bf16, hprev fp32; writes h fp32 (output) and
// bf16 copy (for the q GEMM). 8 elems/thread.
__global__ __launch_bounds__(256) void gru_kernel(
    const u16* __restrict__ gi, const u16* __restrict__ gh,
    const float* __restrict__ hprev, float* __restrict__ houtf,
    u16* __restrict__ houtb, int H)
{
    const size_t idx = ((size_t)blockIdx.x * 256 + threadIdx.x) * 8;
    const size_t b = idx / H;
    const size_t j = idx - b * H;
    const size_t g0 = b * (size_t)(3 * H) + j;

    u16x8 vir = *(const u16x8*)&gi[g0];
    u16x8 viz = *(const u16x8*)&gi[g0 + H];
    u16x8 vin = *(const u16x8*)&gi[g0 + 2 * H];
    u16x8 vhr = *(const u16x8*)&gh[g0];
    u16x8 vhz = *(const u16x8*)&gh[g0 + H];
    u16x8 vhn = *(const u16x8*)&gh[g0 + 2 * H];
    float4 hp0 = *(const float4*)&hprev[idx];
    float4 hp1 = *(const float4*)&hprev[idx + 4];
    float hp[8] = {hp0.x, hp0.y, hp0.z, hp0.w, hp1.x, hp1.y, hp1.z, hp1.w};
    float ho[8];
    u16x8 ob;
#pragma unroll
    for (int i = 0; i < 8; ++i) {
        float r = 1.f / (1.f + expf(-(b2f(vir[i]) + b2f(vhr[i]))));
        float z = 1.f / (1.f + expf(-(b2f(viz[i]) + b2f(vhz[i]))));
        float n = tanhf(b2f(vin[i]) + r * b2f(vhn[i]));
        float h = (1.f - z) * n + z * hp[i];
        ho[i] = h;
        ob[i] = f2b(h);
    }
    *(float4*)&houtf[idx]     = make_float4(ho[0], ho[1], ho[2], ho[3]);
    *(float4*)&houtf[idx + 4] = make_float4(ho[4], ho[5], ho[6], ho[7]);
    *(u16x8*)&houtb[idx] = ob;
}

// Decode: per row i of q[4096,4096] (bf16):
//   out[2i,  j] = max(q[i, j..j+63])                 (windows, j<64)
//   out[2i+1,j] = max over m with m % 64 == (j-1)%64 (strided residue class)
__global__ __launch_bounds__(256) void decode_kernel(
    const u16* __restrict__ q, float* __restrict__ out)
{
    __shared__ float s[4096];
    const int row = blockIdx.x;
    const int t = threadIdx.x;
    const size_t base = (size_t)row * 4096;
#pragma unroll
    for (int i = 0; i < 16; ++i) {
        int j = t + i * 256;
        s[j] = b2f(q[base + j]);
    }
    __syncthreads();
    if (t < 64) {
        float m = -INFINITY;
#pragma unroll 8
        for (int k = 0; k < 64; ++k) m = fmaxf(m, s[t + k]);
        out[(size_t)(2 * row) * 64 + t] = m;
    } else if (t < 128) {
        const int rr = t - 64;
        float m = -INFINITY;
#pragma unroll 8
        for (int k = 0; k < 64; ++k) m = fmaxf(m, s[rr + 64 * k]);
        const int j = (rr + 1) & 63;   // residue rr corresponds to output col j
        out[(size_t)(2 * row + 1) * 64 + j] = m;
    }
}

extern "C" void kernel_launch(void* const* d_in, const int* in_sizes, int n_in,
                              void* d_out, int out_size, void* d_ws, size_t ws_size,
                              hipStream_t stream) {
    constexpr int Bn = 4096, IN = 1024, H = 2048, A = 64, A2 = A * A;
    constexpr size_t BH  = (size_t)Bn * H;        //  8,388,608
    constexpr size_t H3H = (size_t)3 * H * H;     // 12,582,912
    constexpr size_t HIN = (size_t)H * IN;        //  2,097,152
    constexpr size_t BIN = (size_t)Bn * IN;       //  4,194,304
    constexpr size_t A2H = (size_t)A2 * H;        //  8,388,608
    constexpr size_t B3H = (size_t)Bn * 3 * H;    // 25,165,824
    constexpr size_t BA2 = (size_t)Bn * A2;       // 16,777,216

    const float* inputs = (const float*)d_in[0];
    const float* h0     = (const float*)d_in[1];
    const float* W1     = (const float*)d_in[2];
    const float* b1     = (const float*)d_in[3];
    const float* Wih    = (const float*)d_in[4];
    const float* Whh    = (const float*)d_in[5];
    const float* bih    = (const float*)d_in[6];
    const float* bhh    = (const float*)d_in[7];
    const float* W2     = (const float*)d_in[8];
    const float* b2     = (const float*)d_in[9];

    float* out  = (float*)d_out;                 // [2B, A] fp32
    float* hout = out + (size_t)2 * Bn * A;      // [B, H] fp32 (output 1)

    // ws layout (u16 elems), phase-overlaid — peak ~176 MB:
    u16* wsu  = (u16*)d_ws;
    u16* h0b  = wsu;                  // phase 1: [B,H]
    u16* Whhb = wsu + BH;             // phase 1: [3H,H]   (region A = BH+H3H)
    u16* Wihb = wsu;                  // phase 2: [3H,H]   (overlays h0b/Whhb)
    u16* W1b  = wsu + H3H;            // phase 2: [H,IN]
    u16* inb  = wsu + H3H + HIN;      // phase 2: [B,IN]   (18.9M <= 21.0M ok)
    u16* x    = wsu + BH + H3H;       // [B,H]
    u16* gi   = x + BH;               // [B,3H]
    u16* gh   = gi + B3H;             // [B,3H]
    u16* hbf  = gh + B3H;             // [B,H]
    u16* q    = gi;                   // [B,A2] reuses gi after GRU
    u16* W2b  = gi + BA2;             // [A2,H] in gi tail (exactly fills it)

    dim3 blk(256);
    // phase 1: gh = h0 @ Whh^T + bhh
    cvt_kernel<<<dim3(BH  / 2048), blk, 0, stream>>>(h0,  h0b);
    cvt_kernel<<<dim3(H3H / 2048), blk, 0, stream>>>(Whh, Whhb);
    gemm_bt<false><<<dim3(3 * H / 128, Bn / 128), blk, 0, stream>>>(
        h0b, Whhb, bhh, gh, Bn, 3 * H, H);
    // phase 2: x = relu(inputs @ W1^T + b1); gi = x @ Wih^T + bih
    cvt_kernel<<<dim3(HIN / 2048), blk, 0, stream>>>(W1, W1b);
    cvt_kernel<<<dim3(BIN / 2048), blk, 0, stream>>>(inputs, inb);
    cvt_kernel<<<dim3(H3H / 2048), blk, 0, stream>>>(Wih, Wihb);
    gemm_bt<true><<<dim3(H / 128, Bn / 128), blk, 0, stream>>>(
        inb, W1b, b1, x, Bn, H, IN);
    gemm_bt<false><<<dim3(3 * H / 128, Bn / 128), blk, 0, stream>>>(
        x, Wihb, bih, gi, Bn, 3 * H, H);
    // GRU -> h (fp32 into d_out, bf16 copy into ws); frees gi
    gru_kernel<<<dim3((Bn * H / 8) / 256), blk, 0, stream>>>(
        gi, gh, h0, hout, hbf, H);
    // phase 3: q = h @ W2^T + b2 (W2b lives in gi tail, q in gi head)
    cvt_kernel<<<dim3(A2H / 2048), blk, 0, stream>>>(W2, W2b);
    gemm_bt<false><<<dim3(A2 / 128, Bn / 128), blk, 0, stream>>>(
        hbf, W2b, b2, q, Bn, A2, H);
    // decode maxes -> out (fp32)
    decode_kernel<<<dim3(Bn), blk, 0, stream>>>(q, out);
}

// Round 7
// 527.323 us; speedup vs baseline: 1.7109x; 1.1443x over previous
//
#include <hip/hip_runtime.h>
#include <stdint.h>

typedef unsigned short u16;
typedef __bf16 bf16x8 __attribute__((ext_vector_type(8)));
typedef float f32x4 __attribute__((ext_vector_type(4)));
typedef u16 u16x8 __attribute__((ext_vector_type(8)));

__device__ __forceinline__ float b2f(u16 v) {
    union { float f; unsigned int u; } x; x.u = ((unsigned int)v) << 16; return x.f;
}
__device__ __forceinline__ u16 f2b(float f) {
    union { float f; unsigned int u; } x; x.f = f;
    unsigned int r = x.u + 0x7fff + ((x.u >> 16) & 1);
    return (u16)(r >> 16);
}

__device__ __forceinline__ void gll16(const void* g, void* l) {
    __builtin_amdgcn_global_load_lds(
        (const __attribute__((address_space(1))) void*)g,
        (__attribute__((address_space(3))) void*)l,
        16, 0, 0);
}

// fp32x8 -> bf16x8, round-half-up (hi16(bits+0x8000)), packed via v_perm_b32.
__device__ __forceinline__ bf16x8 pack8(float4 f0, float4 f1) {
    union { float4 f; uint4 u; } a, b;
    a.f = f0; b.f = f1;
    const unsigned sel = 0x07060302u;   // D = {s0.hi16, s1.hi16}
    union { unsigned u[4]; bf16x8 v; } r;
    r.u[0] = __builtin_amdgcn_perm(a.u.y + 0x8000u, a.u.x + 0x8000u, sel);
    r.u[1] = __builtin_amdgcn_perm(a.u.w + 0x8000u, a.u.z + 0x8000u, sel);
    r.u[2] = __builtin_amdgcn_perm(b.u.y + 0x8000u, b.u.x + 0x8000u, sel);
    r.u[3] = __builtin_amdgcn_perm(b.u.w + 0x8000u, b.u.z + 0x8000u, sel);
    return r.v;
}

// fp32 -> bf16 bulk convert, 8 elems/thread (n must be multiple of 2048).
__global__ __launch_bounds__(256) void cvt_kernel(
    const float* __restrict__ s, u16* __restrict__ d)
{
    const size_t i = ((size_t)blockIdx.x * 256 + threadIdx.x) * 8;
    float4 f0 = *(const float4*)(s + i);
    float4 f1 = *(const float4*)(s + i + 4);
    union { bf16x8 v; u16x8 u; } r;
    r.v = pack8(f0, f1);
    *(u16x8*)(d + i) = r.u;
}

// NT GEMM, pure bf16: C[M,N] = act(A[M,K] * B[N,K]^T + bias[N]), fp32 accum.
// M,N mult of 128; K mult of 64. 256 thr, 4 waves 2x2, wave=64x64 (4x4 MFMA),
// BK=64 (2 MFMA k-steps per staged tile -> half the barrier/drain overhead).
// Staging: global_load_lds DMA, 16B chunks, XOR-swizzled bf16 LDS tile
// [128][64]: phys_chunk = r*8 + (c ^ (r&7))  (chunk = 8 bf16).
template <bool RELU>
__global__ __launch_bounds__(256, 4) void gemm_bt(
    const u16* __restrict__ A, const u16* __restrict__ Bw,
    const float* __restrict__ bias, u16* __restrict__ C,
    int M, int N, int K)
{
    __shared__ alignas(16) u16 sA[128 * 64];
    __shared__ alignas(16) u16 sB[128 * 64];

    const int t = threadIdx.x;
    const int l = t & 63;
    const int w = t >> 6;
    const int mBase = blockIdx.y * 128;
    const int nBase = blockIdx.x * 128;
    const int wr = w >> 1, wc = w & 1;

    f32x4 acc[4][4] = {};

    const int frow = l & 15;
    const int cIdx = l >> 4;          // which 8-elem K-group this lane holds

    for (int k0 = 0; k0 < K; k0 += 64) {
#pragma unroll
        for (int i = 0; i < 4; ++i) {
            const int phys = i * 256 + t;
            const int r = phys >> 3;
            const int c = (phys & 7) ^ (r & 7);
            gll16(A + (size_t)(mBase + r) * K + (k0 + c * 8),
                  (char*)sA + (i * 256 + w * 64) * 16);
            gll16(Bw + (size_t)(nBase + r) * K + (k0 + c * 8),
                  (char*)sB + (i * 256 + w * 64) * 16);
        }

        __syncthreads();   // drains vmcnt -> DMA landed; LDS consistent

#pragma unroll
        for (int s = 0; s < 2; ++s) {
            bf16x8 af[4], bf[4];
#pragma unroll
            for (int rr = 0; rr < 4; ++rr) {
                const int fr = wr * 64 + rr * 16 + frow;
                af[rr] = *(const bf16x8*)((char*)sA +
                         (fr * 8 + ((s * 4 + cIdx) ^ (fr & 7))) * 16);
            }
#pragma unroll
            for (int cc = 0; cc < 4; ++cc) {
                const int fr = wc * 64 + cc * 16 + frow;
                bf[cc] = *(const bf16x8*)((char*)sB +
                         (fr * 8 + ((s * 4 + cIdx) ^ (fr & 7))) * 16);
            }
#pragma unroll
            for (int r = 0; r < 4; ++r)
#pragma unroll
                for (int c = 0; c < 4; ++c)
                    acc[r][c] = __builtin_amdgcn_mfma_f32_16x16x32_bf16(
                        af[r], bf[c], acc[r][c], 0, 0, 0);
        }

        __syncthreads();   // reads done before next iter's DMA overwrites LDS
    }

    // epilogue: C/D layout col = l&15, row = (l>>4)*4 + reg
    const int rquad = (l >> 4) * 4;
#pragma unroll
    for (int c = 0; c < 4; ++c) {
        const int col = nBase + wc * 64 + c * 16 + (l & 15);
        const float bv = bias[col];
#pragma unroll
        for (int r = 0; r < 4; ++r) {
            const int row = mBase + wr * 64 + r * 16 + rquad;
#pragma unroll
            for (int i = 0; i < 4; ++i) {
                float v = acc[r][c][i] + bv;
                if (RELU) v = fmaxf(v, 0.0f);
                C[(size_t)(row + i) * N + col] = f2b(v);
            }
        }
    }
}

// GRU elementwise: r = sig(ir+hr); z = sig(iz+hz); n = tanh(inn + r*hn);
// h = (1-z)*n + z*h_prev. gi/gh bf16, hprev fp32; writes h fp32 (output) and
// bf16 copy (for the q GEMM). 8 elems/thread.
__global__ __launch_bounds__(256) void gru_kernel(
    const u16* __restrict__ gi, const u16* __restrict__ gh,
    const float* __restrict__ hprev, float* __restrict__ houtf,
    u16* __restrict__ houtb, int H)
{
    const size_t idx = ((size_t)blockIdx.x * 256 + threadIdx.x) * 8;
    const size_t b = idx / H;
    const size_t j = idx - b * H;
    const size_t g0 = b * (size_t)(3 * H) + j;

    u16x8 vir = *(const u16x8*)&gi[g0];
    u16x8 viz = *(const u16x8*)&gi[g0 + H];
    u16x8 vin = *(const u16x8*)&gi[g0 + 2 * H];
    u16x8 vhr = *(const u16x8*)&gh[g0];
    u16x8 vhz = *(const u16x8*)&gh[g0 + H];
    u16x8 vhn = *(const u16x8*)&gh[g0 + 2 * H];
    float4 hp0 = *(const float4*)&hprev[idx];
    float4 hp1 = *(const float4*)&hprev[idx + 4];
    float hp[8] = {hp0.x, hp0.y, hp0.z, hp0.w, hp1.x, hp1.y, hp1.z, hp1.w};
    float ho[8];
    u16x8 ob;
#pragma unroll
    for (int i = 0; i < 8; ++i) {
        float r = 1.f / (1.f + expf(-(b2f(vir[i]) + b2f(vhr[i]))));
        float z = 1.f / (1.f + expf(-(b2f(viz[i]) + b2f(vhz[i]))));
        float n = tanhf(b2f(vin[i]) + r * b2f(vhn[i]));
        float h = (1.f - z) * n + z * hp[i];
        ho[i] = h;
        ob[i] = f2b(h);
    }
    *(float4*)&houtf[idx]     = make_float4(ho[0], ho[1], ho[2], ho[3]);
    *(float4*)&houtf[idx + 4] = make_float4(ho[4], ho[5], ho[6], ho[7]);
    *(u16x8*)&houtb[idx] = ob;
}

// Decode: per row i of q[4096,4096] (bf16):
//   out[2i,  j] = max(q[i, j..j+63])                 (windows, j<64)
//   out[2i+1,j] = max over m with m % 64 == (j-1)%64 (strided residue class)
__global__ __launch_bounds__(256) void decode_kernel(
    const u16* __restrict__ q, float* __restrict__ out)
{
    __shared__ float s[4096];
    const int row = blockIdx.x;
    const int t = threadIdx.x;
    const size_t base = (size_t)row * 4096;
#pragma unroll
    for (int i = 0; i < 16; ++i) {
        int j = t + i * 256;
        s[j] = b2f(q[base + j]);
    }
    __syncthreads();
    if (t < 64) {
        float m = -INFINITY;
#pragma unroll 8
        for (int k = 0; k < 64; ++k) m = fmaxf(m, s[t + k]);
        out[(size_t)(2 * row) * 64 + t] = m;
    } else if (t < 128) {
        const int rr = t - 64;
        float m = -INFINITY;
#pragma unroll 8
        for (int k = 0; k < 64; ++k) m = fmaxf(m, s[rr + 64 * k]);
        const int j = (rr + 1) & 63;   // residue rr corresponds to output col j
        out[(size_t)(2 * row + 1) * 64 + j] = m;
    }
}

extern "C" void kernel_launch(void* const* d_in, const int* in_sizes, int n_in,
                              void* d_out, int out_size, void* d_ws, size_t ws_size,
                              hipStream_t stream) {
    constexpr int Bn = 4096, IN = 1024, H = 2048, A = 64, A2 = A * A;
    constexpr size_t BH  = (size_t)Bn * H;        //  8,388,608
    constexpr size_t H3H = (size_t)3 * H * H;     // 12,582,912
    constexpr size_t HIN = (size_t)H * IN;        //  2,097,152
    constexpr size_t BIN = (size_t)Bn * IN;       //  4,194,304
    constexpr size_t A2H = (size_t)A2 * H;        //  8,388,608
    constexpr size_t B3H = (size_t)Bn * 3 * H;    // 25,165,824
    constexpr size_t BA2 = (size_t)Bn * A2;       // 16,777,216

    const float* inputs = (const float*)d_in[0];
    const float* h0     = (const float*)d_in[1];
    const float* W1     = (const float*)d_in[2];
    const float* b1     = (const float*)d_in[3];
    const float* Wih    = (const float*)d_in[4];
    const float* Whh    = (const float*)d_in[5];
    const float* bih    = (const float*)d_in[6];
    const float* bhh    = (const float*)d_in[7];
    const float* W2     = (const float*)d_in[8];
    const float* b2     = (const float*)d_in[9];

    float* out  = (float*)d_out;                 // [2B, A] fp32
    float* hout = out + (size_t)2 * Bn * A;      // [B, H] fp32 (output 1)

    // ws layout (u16 elems), phase-overlaid — peak ~176 MB:
    u16* wsu  = (u16*)d_ws;
    u16* h0b  = wsu;                  // phase 1: [B,H]
    u16* Whhb = wsu + BH;             // phase 1: [3H,H]   (region A = BH+H3H)
    u16* Wihb = wsu;                  // phase 2: [3H,H]   (overlays h0b/Whhb)
    u16* W1b  = wsu + H3H;            // phase 2: [H,IN]
    u16* inb  = wsu + H3H + HIN;      // phase 2: [B,IN]   (18.9M <= 21.0M ok)
    u16* x    = wsu + BH + H3H;       // [B,H]
    u16* gi   = x + BH;               // [B,3H]
    u16* gh   = gi + B3H;             // [B,3H]
    u16* hbf  = gh + B3H;             // [B,H]
    u16* q    = gi;                   // [B,A2] reuses gi after GRU
    u16* W2b  = gi + BA2;             // [A2,H] in gi tail (exactly fills it)

    dim3 blk(256);
    // phase 1: gh = h0 @ Whh^T + bhh
    cvt_kernel<<<dim3(BH  / 2048), blk, 0, stream>>>(h0,  h0b);
    cvt_kernel<<<dim3(H3H / 2048), blk, 0, stream>>>(Whh, Whhb);
    gemm_bt<false><<<dim3(3 * H / 128, Bn / 128), blk, 0, stream>>>(
        h0b, Whhb, bhh, gh, Bn, 3 * H, H);
    // phase 2: x = relu(inputs @ W1^T + b1); gi = x @ Wih^T + bih
    cvt_kernel<<<dim3(HIN / 2048), blk, 0, stream>>>(W1, W1b);
    cvt_kernel<<<dim3(BIN / 2048), blk, 0, stream>>>(inputs, inb);
    cvt_kernel<<<dim3(H3H / 2048), blk, 0, stream>>>(Wih, Wihb);
    gemm_bt<true><<<dim3(H / 128, Bn / 128), blk, 0, stream>>>(
        inb, W1b, b1, x, Bn, H, IN);
    gemm_bt<false><<<dim3(3 * H / 128, Bn / 128), blk, 0, stream>>>(
        x, Wihb, bih, gi, Bn, 3 * H, H);
    // GRU -> h (fp32 into d_out, bf16 copy into ws); frees gi
    gru_kernel<<<dim3((Bn * H / 8) / 256), blk, 0, stream>>>(
        gi, gh, h0, hout, hbf, H);
    // phase 3: q = h @ W2^T + b2 (W2b lives in gi tail, q in gi head)
    cvt_kernel<<<dim3(A2H / 2048), blk, 0, stream>>>(W2, W2b);
    gemm_bt<false><<<dim3(A2 / 128, Bn / 128), blk, 0, stream>>>(
        hbf, W2b, b2, q, Bn, A2, H);
    // decode maxes -> out (fp32)
    decode_kernel<<<dim3(Bn), blk, 0, stream>>>(q, out);
}